// Round 1
// baseline (319.373 us; speedup 1.0000x reference)
//
#include <hip/hip_runtime.h>
#include <math.h>

// ToMe merge, B=64 T=577 C=1024, f32 in / f32 out (world established R3/R4).
// r=288 => unm={token 0}; out[b][0]=x[b][0]; out[b][1+j] = mean(odd token
// 2j+1, evens i>=1 with argmax_j cos(a_i,b_j)==j), numpy first-index ties.
//
// R7: (a) k_scores depth-2 register prefetch. R6's depth-1 "pipeline" never
// materialized: VGPR_Count=76 < 48 (L) + 24 (frags) + addressing, so the
// scheduler sank the global loads to just before the pack -> every chunk
// exposed full L2/HBM latency behind a vmcnt(0) (93us at 5.7% MfmaUtil, all
// BW ceilings <20%). Now: two register sets SA/SB, loads for chunk k+2
// issued in the barrier interval of chunk k, consumed (pack+ds_write) one
// full interval later -> loads cannot sink across __syncthreads (which
// drains only lgkmcnt for plain VGPR loads), compiler emits precise
// vmcnt(12). Loop is 2x-unrolled, branchless (chunks 14/15 peeled) so the
// waitcnt pass never merges guarded paths into vmcnt(0). sched_barrier(0)
// pins load-issue above the stage. Stage placed before MFMA keeps peak regs
// ~130 VGPR + 36 AGPR -> still 3 waves/SIMD (LDS caps 3 blocks/CU).
// (b) EPS_MARGIN 0.04 -> 0.01: candidates within eps of a Gaussian row-max
// scale as e^{92*eps} (~40/row at 0.04, ~2.5/row at 0.01); bf16-truncation
// score error <= ~1.5e-3 so 0.01 keeps >=6x margin. Cuts k_recheck's exact
// f64 path and k_scores' extras atomics by ~10x.
// Candidate scheme unchanged (R5, passed): per-row 48-col group winner u64 +
// extras within EPS of group max; k_recheck resolves with exact f64 when >1
// candidate within EPS of global stage-1 max.

#define B_   64
#define T_   577
#define C_   1024
#define NA   289
#define NB   288
#define EPS_MARGIN 0.01f

#define RPAD 384                 // 4 row-tiles x 96
#define EXTRA_CAP 12

typedef __bf16 bf16x8 __attribute__((ext_vector_type(8)));
typedef float  floatx4 __attribute__((ext_vector_type(4)));
typedef unsigned long long u64;

// ws layout (bytes)
#define ECNT_OFF   0                                  // u32[64*384]   98304
#define GRPWIN_OFF 98304                              // u64[64*384*6] 1179648
#define EXTRA_OFF  (GRPWIN_OFF + 1179648)             // u64[64*384*12] 2359296
#define DST_OFF    (EXTRA_OFF + 2359296)              // int[64*NA]

__device__ __forceinline__ u64 shfl_xor_u64(u64 v, int msk) {
  unsigned int lo = (unsigned int)v, hi = (unsigned int)(v >> 32);
  lo = __shfl_xor(lo, msk, 64);
  hi = __shfl_xor(hi, msk, 64);
  return ((u64)hi << 32) | (u64)lo;
}
__device__ __forceinline__ double shfl_xor_f64(double v, int msk) {
  u64 u = __double_as_longlong(v);
  return __longlong_as_double((long long)shfl_xor_u64(u, msk));
}

__device__ __forceinline__ unsigned int fkey(float s) {
  unsigned int fb = __float_as_uint(s);
  return (fb & 0x80000000u) ? ~fb : (fb | 0x80000000u);
}
__device__ __forceinline__ float keyf(unsigned int k) {
  return (k & 0x80000000u) ? __uint_as_float(k ^ 0x80000000u) : __uint_as_float(~k);
}
__device__ __forceinline__ u64 packsc(float s, int col) {
  return ((u64)fkey(s) << 32) | (u64)(0xFFFFFFFFu - (unsigned int)col);
}
__device__ __forceinline__ int pcol(u64 p) {
  return (int)(0xFFFFFFFFu - (unsigned int)(p & 0xFFFFFFFFull));
}
__device__ __forceinline__ float pscore(u64 p) { return keyf((unsigned int)(p >> 32)); }

// two f32 -> two truncated bf16 packed in one dword
__device__ __forceinline__ unsigned int pk_bf16_trunc(unsigned int e1, unsigned int e0) {
  return __builtin_amdgcn_perm(e1, e0, 0x07060302u);
}

__device__ __forceinline__ void load16f(const float* x, size_t off, float* v) {
  const float4* p = (const float4*)(x + off);
  float4 a = p[0], b = p[1], c = p[2], d = p[3];
  v[0]=a.x; v[1]=a.y; v[2]=a.z; v[3]=a.w;
  v[4]=b.x; v[5]=b.y; v[6]=b.z; v[7]=b.w;
  v[8]=c.x; v[9]=c.y; v[10]=c.z; v[11]=c.w;
  v[12]=d.x; v[13]=d.y; v[14]=d.z; v[15]=d.w;
}

// ---------------------------------------------------------------------------
// k_scores: grid (64, 4 row-tiles, 3 col-tiles), 256 thr. 96x96 tile, BK=64,
// 16 chunks, double-buffered LDS, depth-2 register prefetch. XOR swizzle:
// physical slot s of LDS row r holds k-granule s^(r&7) (granule = 8 bf16 =
// 16B) -> conflict-free ds_read_b128 (verified: 0 conflicts R4/R5).
// Same-batch blocks share linear%8 -> same XCD.
// Wave w: i-tiles (w>>1)*3..+2, j-tiles (w&1)*3..+2, 9 accs.
// A/B frag: row/col = lane&15, k=(lane>>4)*8+e. C/D: col=lane&15,
// row=(lane>>4)*4+reg  [m89/m91].
// ---------------------------------------------------------------------------

// issue 12 dwordx4 loads for chunk KCC into register set S (6 x 32B)
#define LOADC(S, KCC) do {                                                    \
  _Pragma("unroll")                                                           \
  for (int e_ = 0; e_ < 6; ++e_) {                                            \
    const uint4* p_ = (const uint4*)(eptr[e_] + (KCC) * 64);                  \
    S[e_][0] = p_[0]; S[e_][1] = p_[1];                                       \
  }                                                                           \
} while (0)

// pack set S to bf16 and store to LDS buffer BUFP; accumulate sumsq partials
#define STAGEC(S, BUFP) do {                                                  \
  unsigned char* sb_ = (BUFP);                                                \
  _Pragma("unroll")                                                           \
  for (int e_ = 0; e_ < 6; ++e_) {                                            \
    uint4 lo_ = S[e_][0], hi_ = S[e_][1];                                     \
    uint4 o_;                                                                 \
    o_.x = pk_bf16_trunc(lo_.y, lo_.x);                                       \
    o_.y = pk_bf16_trunc(lo_.w, lo_.z);                                       \
    o_.z = pk_bf16_trunc(hi_.y, hi_.x);                                       \
    o_.w = pk_bf16_trunc(hi_.w, hi_.z);                                       \
    *(uint4*)(sb_ + eoff[e_]) = o_;                                           \
    if (e_ >= 3) {                                                            \
      float f0_ = __uint_as_float(lo_.x), f1_ = __uint_as_float(lo_.y);       \
      float f2_ = __uint_as_float(lo_.z), f3_ = __uint_as_float(lo_.w);       \
      float f4_ = __uint_as_float(hi_.x), f5_ = __uint_as_float(hi_.y);       \
      float f6_ = __uint_as_float(hi_.z), f7_ = __uint_as_float(hi_.w);       \
      ssp[e_-3] += f0_*f0_ + f1_*f1_ + f2_*f2_ + f3_*f3_                      \
                 + f4_*f4_ + f5_*f5_ + f6_*f6_ + f7_*f7_;                     \
    }                                                                         \
  }                                                                           \
} while (0)

// one chunk's MFMA phase from LDS buffer BUFP
#define MFMAC(BUFP) do {                                                      \
  const unsigned char* buf_ = (BUFP);                                         \
  _Pragma("unroll")                                                           \
  for (int s_ = 0; s_ < 2; ++s_) {                                            \
    int slot_ = (s_ * 4 + q) ^ sw;                                            \
    bf16x8 af_[3], bg_[3];                                                    \
    _Pragma("unroll")                                                         \
    for (int ii_ = 0; ii_ < 3; ++ii_)                                         \
      af_[ii_] = *(const bf16x8*)(buf_ + ((ib + ii_) * 16 + m) * 128 + slot_ * 16); \
    _Pragma("unroll")                                                         \
    for (int jj_ = 0; jj_ < 3; ++jj_)                                         \
      bg_[jj_] = *(const bf16x8*)(buf_ + 12288 + ((jb + jj_) * 16 + m) * 128 + slot_ * 16); \
    _Pragma("unroll")                                                         \
    for (int ii_ = 0; ii_ < 3; ++ii_)                                         \
      _Pragma("unroll")                                                       \
      for (int jj_ = 0; jj_ < 3; ++jj_)                                       \
        acc[ii_][jj_] = __builtin_amdgcn_mfma_f32_16x16x32_bf16(af_[ii_], bg_[jj_], acc[ii_][jj_], 0, 0, 0); \
  }                                                                           \
} while (0)

__global__ __launch_bounds__(256, 2) void k_scores(const float* __restrict__ x,
                                                   u64* __restrict__ grpwin,
                                                   unsigned int* __restrict__ ecnt,
                                                   u64* __restrict__ extras) {
  __shared__ unsigned char smem[2][24576];  // per buf: A 96x128B @0, B @12288
  __shared__ float sumsq[96];
  int tid = threadIdx.x;
  int b  = blockIdx.x;
  int rt = blockIdx.y;                      // 0..3
  int ct = blockIdx.z;                      // 0..2
  int wv = tid >> 6, lane = tid & 63;
  int m = lane & 15, q = lane >> 4;
  int sw = m & 7;

  if (tid < 96) sumsq[tid] = 0.f;

  // fixed staging assignment: entry e -> v = tid + 256e; e>=3 are B rows
  const float* eptr[6];
  int eoff[6];
#pragma unroll
  for (int e = 0; e < 6; ++e) {
    int v = tid + 256 * e;
    int isB = v >= 768;
    int w = isB ? v - 768 : v;
    int row = w >> 3, slot = w & 7;
    int gk = slot ^ (row & 7);
    int tok;
    if (isB) tok = 2 * (ct * 96 + row) + 1;
    else { tok = 2 * (rt * 96 + row); if (tok > 576) tok = 576; }
    eptr[e] = x + (size_t)(b * T_ + tok) * C_ + gk * 8;
    eoff[e] = (isB ? 12288 : 0) + row * 128 + slot * 16;
  }

  float ssp[3] = {0.f, 0.f, 0.f};
  uint4 SA[6][2], SB[6][2];

  floatx4 acc[3][3];
#pragma unroll
  for (int ii = 0; ii < 3; ++ii)
#pragma unroll
    for (int jj = 0; jj < 3; ++jj) acc[ii][jj] = (floatx4){0,0,0,0};

  const int ib = (wv >> 1) * 3;
  const int jb = (wv & 1) * 3;

  // prologue: chunk0 -> SA, chunk1 -> SB (stays in flight), stage chunk0
  LOADC(SA, 0);
  LOADC(SB, 1);
  __builtin_amdgcn_sched_barrier(0);
  STAGEC(SA, smem[0]);                      // waits vmcnt(12): SB in flight
  __syncthreads();

  // main loop: branchless, 2 chunks per iteration, loads 2 chunks ahead
  for (int kc2 = 0; kc2 < 14; kc2 += 2) {
    // interval A: compute chunk kc2 (smem[0]); stage kc2+1; load kc2+2
    LOADC(SA, kc2 + 2);
    __builtin_amdgcn_sched_barrier(0);
    STAGEC(SB, smem[1]);                    // vmcnt(12): SB done, SA in flight
    MFMAC(smem[0]);
    __syncthreads();
    // interval B: compute chunk kc2+1 (smem[1]); stage kc2+2; load kc2+3
    LOADC(SB, kc2 + 3);
    __builtin_amdgcn_sched_barrier(0);
    STAGEC(SA, smem[0]);
    MFMAC(smem[1]);
    __syncthreads();
  }
  // tail: SB holds chunk 15; smem[0] holds chunk 14
  STAGEC(SB, smem[1]);                      // chunk 15
  MFMAC(smem[0]);                           // chunk 14
  __syncthreads();
  MFMAC(smem[1]);                           // chunk 15

  // fold sumsq partials (3 fixed B-rows per thread, 8 threads per row)
#pragma unroll
  for (int e = 3; e < 6; ++e) {
    int w = tid + 256 * e - 768;
    atomicAdd(&sumsq[w >> 3], ssp[e-3]);
  }
  __syncthreads();

  // epilogue: normalize, per-row argmax over this wave's 48 cols
  float rn[3];
#pragma unroll
  for (int jj = 0; jj < 3; ++jj) rn[jj] = rsqrtf(sumsq[(jb + jj) * 16 + m]);

  int g = ct * 2 + (wv & 1);                // col-group id 0..5
#pragma unroll
  for (int ii = 0; ii < 3; ++ii) {
#pragma unroll
    for (int r = 0; r < 4; ++r) {
      u64 pj[3];
#pragma unroll
      for (int jj = 0; jj < 3; ++jj) {
        float s = acc[ii][jj][r] * rn[jj];
        pj[jj] = packsc(s, ct * 96 + (jb + jj) * 16 + m);
      }
      u64 pk = pj[0];
      if (pj[1] > pk) pk = pj[1];
      if (pj[2] > pk) pk = pj[2];
#pragma unroll
      for (int d = 1; d < 16; d <<= 1) {
        u64 o = shfl_xor_u64(pk, d);
        if (o > pk) pk = o;
      }
      int grow = rt * 96 + (ib + ii) * 16 + q * 4 + r;
      float thr = pscore(pk) - EPS_MARGIN;
      size_t rbase = (size_t)b * RPAD + grow;
#pragma unroll
      for (int jj = 0; jj < 3; ++jj) {
        if (pj[jj] != pk && pscore(pj[jj]) >= thr) {
          unsigned int idx = atomicAdd(&ecnt[rbase], 1u);
          if (idx < EXTRA_CAP) extras[rbase * EXTRA_CAP + idx] = pj[jj];
        }
      }
      if (m == 0) grpwin[rbase * 6 + g] = pk;
    }
  }
}

// ---------------------------------------------------------------------------
// k_recheck: wave per row i in [1,288]. Stage-1 max over 6 group winners;
// candidates = winners+extras within EPS. 1 candidate -> done. Else exact
// f64 dot/||b|| per candidate (tie -> lowest col).
// ---------------------------------------------------------------------------
__global__ __launch_bounds__(256) void k_recheck(const float* __restrict__ x,
                                                 const u64* __restrict__ grpwin,
                                                 const unsigned int* __restrict__ ecnt,
                                                 const u64* __restrict__ extras,
                                                 int* __restrict__ dst) {
  int wid = threadIdx.x >> 6, lane = threadIdx.x & 63;
  int gw = blockIdx.x * 4 + wid;            // grid = B*NB/4
  int b = gw / NB, i = gw - b * NB + 1;     // i in [1,288]
  size_t rbase = (size_t)b * RPAD + i;

  u64 v = (lane < 6) ? grpwin[rbase * 6 + lane] : 0ull;
#pragma unroll
  for (int d = 1; d < 8; d <<= 1) {
    u64 o = shfl_xor_u64(v, d);
    if (o > v) v = o;
  }
  {
    unsigned int lo = (unsigned int)v, hi = (unsigned int)(v >> 32);
    lo = __shfl(lo, 0, 64); hi = __shfl(hi, 0, 64);
    v = ((u64)hi << 32) | lo;
  }
  float thr = pscore(v) - EPS_MARGIN;

  u64 cand[14]; int nc = 0;
#pragma unroll
  for (int t = 0; t < 6; ++t) {
    u64 w = grpwin[rbase * 6 + t];
    if (pscore(w) >= thr && nc < 14) cand[nc++] = w;
  }
  unsigned int ec = ecnt[rbase]; if (ec > EXTRA_CAP) ec = EXTRA_CAP;
  for (unsigned int t = 0; t < ec; ++t) {
    u64 w = extras[rbase * EXTRA_CAP + t];
    if (pscore(w) >= thr && nc < 14) cand[nc++] = w;
  }

  int best;
  if (nc <= 1) {
    best = pcol(v);
  } else {
    float av[16];
    load16f(x, (size_t)(b * T_ + 2 * i) * C_ + lane * 16, av);
    double bs = -1e300; int bc = 1 << 30;
    for (int c = 0; c < nc; ++c) {
      int col = pcol(cand[c]);
      float bv[16];
      load16f(x, (size_t)(b * T_ + 2 * col + 1) * C_ + lane * 16, bv);
      double dot = 0.0, nsq = 0.0;
#pragma unroll
      for (int t = 0; t < 16; ++t) {
        dot += (double)av[t] * (double)bv[t];
        nsq += (double)bv[t] * (double)bv[t];
      }
#pragma unroll
      for (int d = 32; d >= 1; d >>= 1) {
        dot += shfl_xor_f64(dot, d);
        nsq += shfl_xor_f64(nsq, d);
      }
      double s = dot / sqrt(nsq);
      if (s > bs || (s == bs && col < bc)) { bs = s; bc = col; }
    }
    best = bc;
  }
  if (lane == 0) dst[b * NA + i] = best;
}

// ---------------------------------------------------------------------------
// k_merge: membership lists in LDS, wave per output row.
// ---------------------------------------------------------------------------
__global__ __launch_bounds__(256) void k_merge(const float* __restrict__ x,
                                               const int* __restrict__ dst,
                                               float* __restrict__ out) {
  __shared__ int dstv[NA];
  __shared__ unsigned short lists[4][292];
  __shared__ int cnts[4];
  int b = blockIdx.y, tid = threadIdx.x;
  int orow_base = blockIdx.x * 4;

  for (int i = tid; i < NA; i += 256) dstv[i] = (i >= 1) ? dst[b * NA + i] : -1;
  if (tid < 4) cnts[tid] = 0;
  __syncthreads();

  for (int i = 1 + tid; i <= 288; i += 256) {
    int d = dstv[i];
#pragma unroll
    for (int w4 = 0; w4 < 4; ++w4) {
      int orow_w = orow_base + w4;
      if (orow_w >= 1 && orow_w < NA && d == orow_w - 1) {
        int idx = atomicAdd(&cnts[w4], 1);
        lists[w4][idx] = (unsigned short)i;
      }
    }
  }
  __syncthreads();

  int wv = tid >> 6, lane = tid & 63;
  int orow = orow_base + wv;
  if (orow >= NA) return;

  const size_t xb = (size_t)b * T_ * C_;
  int c0 = lane * 16;
  float acc[16];
  float inv = 1.0f;

  if (orow == 0) {
    load16f(x, xb + c0, acc);
  } else {
    int j = orow - 1;
    load16f(x, xb + (size_t)(2 * j + 1) * C_ + c0, acc);
    int cnt = cnts[wv];
    for (int e = 0; e < cnt; ++e) {
      int i = lists[wv][e];
      float tv[16];
      load16f(x, xb + (size_t)(2 * i) * C_ + c0, tv);
#pragma unroll
      for (int t = 0; t < 16; ++t) acc[t] += tv[t];
    }
    inv = 1.0f / (float)(cnt + 1);
  }

  float4* op = (float4*)(out + ((size_t)b * NA + orow) * C_ + c0);
  op[0] = make_float4(acc[0]*inv,  acc[1]*inv,  acc[2]*inv,  acc[3]*inv);
  op[1] = make_float4(acc[4]*inv,  acc[5]*inv,  acc[6]*inv,  acc[7]*inv);
  op[2] = make_float4(acc[8]*inv,  acc[9]*inv,  acc[10]*inv, acc[11]*inv);
  op[3] = make_float4(acc[12]*inv, acc[13]*inv, acc[14]*inv, acc[15]*inv);
}

// ---------------------------------------------------------------------------
extern "C" void kernel_launch(void* const* d_in, const int* in_sizes, int n_in,
                              void* d_out, int out_size, void* d_ws, size_t ws_size,
                              hipStream_t stream) {
  const float* x = (const float*)d_in[0];
  float* out     = (float*)d_out;
  char* ws = (char*)d_ws;
  unsigned int* ecnt = (unsigned int*)(ws + ECNT_OFF);
  u64* grpwin        = (u64*)(ws + GRPWIN_OFF);
  u64* extras        = (u64*)(ws + EXTRA_OFF);
  int* dst           = (int*)(ws + DST_OFF);

  hipMemsetAsync(ecnt, 0, (size_t)B_ * RPAD * sizeof(unsigned int), stream);
  k_scores <<<dim3(B_, 4, 3), 256, 0, stream>>>(x, grpwin, ecnt, extras);
  k_recheck<<<B_ * NB / 4, 256, 0, stream>>>(x, grpwin, ecnt, extras, dst);
  k_merge  <<<dim3((NA + 3) / 4, B_), 256, 0, stream>>>(x, dst, out);
}